// Round 5
// baseline (74.147 us; speedup 1.0000x reference)
//
#include <hip/hip_runtime.h>

typedef __attribute__((ext_vector_type(8))) short short8;
typedef __attribute__((ext_vector_type(4))) float f32x4;

#define S_LEN 1024
#define B_N 8
#define D_DIM 512
#define SLAB_Y 4194304   // 8192*512 elements per y slab
#define SLAB_W 262144    // 512*512 elements per W slab
#define NW   786432      // W element count

static __device__ __forceinline__ unsigned short f2bf(float f){
  unsigned int u = __float_as_uint(f);
  u = u + 0x7fffu + ((u>>16)&1u);
  return (unsigned short)(u>>16);
}

#define GLL16(g,l) __builtin_amdgcn_global_load_lds( \
    (__attribute__((address_space(1))) void*)(g), \
    (__attribute__((address_space(3))) void*)(l), 16, 0, 0)

// ---------------- gram (blocks [0,512)) + W->bf16 (blocks [512,1280)) ----------------
// gram: Gband[b][i][dl+14] = x[b,i]·x[b,i+dl] (bf16-rounded inputs), |dl|<=14
__global__ __launch_bounds__(256) void k_gramw(const float* __restrict__ x,
    const float* __restrict__ W, float* __restrict__ Gband,
    unsigned short* __restrict__ wbf)
{
  int blk = blockIdx.x;
  int tid = threadIdx.x;
  if (blk >= 512){
    int i = ((blk - 512)*256 + tid)*4;
    float4 v = *(const float4*)(W + i);
    ushort4 hh;
    hh.x = f2bf(v.x); hh.y = f2bf(v.y); hh.z = f2bf(v.z); hh.w = f2bf(v.w);
    *(ushort4*)(wbf + i) = hh;
    return;
  }
  int lane = tid & 63, w = tid >> 6;
  if (w >= 3) return;
  int b = blk & 7, i0 = (blk >> 3) * 16;
  int j0 = i0 + (w - 1) * 16;
  if (j0 < 0 || j0 >= S_LEN) return;
  int l15 = lane & 15, klo = (lane >> 4) * 8;
  const float* Ar = x + ((size_t)(i0 + l15) * B_N + b) * D_DIM + klo;
  const float* Br = x + ((size_t)(j0 + l15) * B_N + b) * D_DIM + klo;
  f32x4 acc = (f32x4){0.f,0.f,0.f,0.f};
  #pragma unroll
  for (int kt = 0; kt < 16; ++kt){
    float4 a0 = *(const float4*)(Ar + kt*32);
    float4 a1 = *(const float4*)(Ar + kt*32 + 4);
    float4 b0 = *(const float4*)(Br + kt*32);
    float4 b1 = *(const float4*)(Br + kt*32 + 4);
    short8 af, bf;
    af[0]=f2bf(a0.x); af[1]=f2bf(a0.y); af[2]=f2bf(a0.z); af[3]=f2bf(a0.w);
    af[4]=f2bf(a1.x); af[5]=f2bf(a1.y); af[6]=f2bf(a1.z); af[7]=f2bf(a1.w);
    bf[0]=f2bf(b0.x); bf[1]=f2bf(b0.y); bf[2]=f2bf(b0.z); bf[3]=f2bf(b0.w);
    bf[4]=f2bf(b1.x); bf[5]=f2bf(b1.y); bf[6]=f2bf(b1.z); bf[7]=f2bf(b1.w);
    acc = __builtin_amdgcn_mfma_f32_16x16x32_bf16(af, bf, acc, 0,0,0);
  }
  int rb = (lane >> 4) * 4;
  #pragma unroll
  for (int rg = 0; rg < 4; ++rg){
    int i = i0 + rb + rg;
    int dl = j0 + l15 - i;
    if (dl >= -14 && dl <= 14)
      Gband[((size_t)b * S_LEN + i) * 32 + dl + 14] = acc[rg];
  }
}

// ---------------- weights + windowed weighted sum: y_m[t] = sum_pos wts*x[pos] ----
// block 256 = 2 halves x 128 threads; half h handles (b, t=tg*2+h)
__global__ __launch_bounds__(256) void k_wsum(const float* __restrict__ x,
    const float* __restrict__ Gband, const float* __restrict__ alphas,
    const float* __restrict__ betas, unsigned short* __restrict__ y,
    float* __restrict__ sw)
{
  int blk = blockIdx.x;           // 4096 = 8 b x 512 tg
  int b = blk & 7, tg = blk >> 3;
  int tid = threadIdx.x, h = tid >> 7, j = tid & 127;
  int t = tg * 2 + h;
  __shared__ float pshare[2][33];
  __shared__ float invc[2][3];
  __shared__ float wsh[2][33];
  int m = 0, pos = 0, valid = 0;
  float pp = 0.f, invnp = 0.f;
  if (j < 33){
    int r, wsl;
    if (j < 7){ m = 0; r = 3; wsl = j; }
    else if (j < 18){ m = 1; r = 5; wsl = j - 7; }
    else { m = 2; r = 7; wsl = j - 18; }
    pos = t + wsl - r;
    valid = (pos >= 0 && pos < S_LEN);
    if (valid){
      const float* grow = Gband + ((size_t)b * S_LEN + pos) * 32;
      int ulo = max(t - r, 0), uhi = min(t + r, S_LEN - 1);
      for (int u = ulo; u <= uhi; ++u) pp += grow[u - pos + 14];
      invnp = rsqrtf(fmaxf(grow[14], 1e-24f));
    }
    pshare[h][j] = valid ? pp : 0.f;
  }
  __syncthreads();
  if (j < 3){
    int s0 = j == 0 ? 0 : (j == 1 ? 7 : 18);
    int c  = j == 0 ? 7 : (j == 1 ? 11 : 15);
    float s = 0.f;
    for (int k = 0; k < c; ++k) s += pshare[h][s0 + k];
    invc[h][j] = rsqrtf(fmaxf(s, 1e-24f));
  }
  __syncthreads();
  if (j < 33){
    float wt = 0.f;
    if (valid){
      float sim = pp * invnp * invc[h][m];
      float z = alphas[m] * sim + betas[m];
      wt = 1.0f / (1.0f + expf(-z));
    }
    wsh[h][j] = wt;
  }
  __syncthreads();
  size_t row = (size_t)t * B_N + b;
  if (j < 3){
    int s0 = j == 0 ? 0 : (j == 1 ? 7 : 18);
    int c  = j == 0 ? 7 : (j == 1 ? 11 : 15);
    float s = 0.f;
    for (int k = 0; k < c; ++k) s += wsh[h][s0 + k];
    sw[(size_t)j * 8192 + row] = s;
  }
  int d0 = j * 4;
  f32x4 y0 = (f32x4){0.f,0.f,0.f,0.f};
  f32x4 y1 = (f32x4){0.f,0.f,0.f,0.f};
  f32x4 y2 = (f32x4){0.f,0.f,0.f,0.f};
  #pragma unroll
  for (int p = 0; p < 33; ++p){
    int pm, pr, wsl;
    if (p < 7){ pm = 0; pr = 3; wsl = p; }
    else if (p < 18){ pm = 1; pr = 5; wsl = p - 7; }
    else { pm = 2; pr = 7; wsl = p - 18; }
    int ppos = t + wsl - pr;
    if (ppos < 0 || ppos >= S_LEN) continue;
    float wt = wsh[h][p];
    const float* xp = x + ((size_t)ppos * B_N + b) * D_DIM + d0;
    float4 xv = *(const float4*)xp;
    if (pm == 0){ y0[0]+=wt*xv.x; y0[1]+=wt*xv.y; y0[2]+=wt*xv.z; y0[3]+=wt*xv.w; }
    else if (pm == 1){ y1[0]+=wt*xv.x; y1[1]+=wt*xv.y; y1[2]+=wt*xv.z; y1[3]+=wt*xv.w; }
    else { y2[0]+=wt*xv.x; y2[1]+=wt*xv.y; y2[2]+=wt*xv.z; y2[3]+=wt*xv.w; }
  }
  ushort4 h0, h1, h2;
  h0.x=f2bf(y0[0]); h0.y=f2bf(y0[1]); h0.z=f2bf(y0[2]); h0.w=f2bf(y0[3]);
  h1.x=f2bf(y1[0]); h1.y=f2bf(y1[1]); h1.z=f2bf(y1[2]); h1.w=f2bf(y1[3]);
  h2.x=f2bf(y2[0]); h2.y=f2bf(y2[1]); h2.z=f2bf(y2[2]); h2.w=f2bf(y2[3]);
  *(ushort4*)(y + 0*(size_t)SLAB_Y + row*D_DIM + d0) = h0;
  *(ushort4*)(y + 1*(size_t)SLAB_Y + row*D_DIM + d0) = h1;
  *(ushort4*)(y + 2*(size_t)SLAB_Y + row*D_DIM + d0) = h2;
}

// ---------------- GEMM: out[row][col] = x + sum_m y_m[row,:]·W_m[col,:] + sum_m sw_m[row]*b_m[col]
// M=8192 N=512 K=1536 (3 slabs of 512). tile 64x128, BK=32, 48 K-steps, 4 waves (2x2)
__global__ __launch_bounds__(256) void k_gemm(const unsigned short* __restrict__ y,
    const unsigned short* __restrict__ wbf, const float* __restrict__ x,
    const float* __restrict__ bias, const float* __restrict__ sw,
    float* __restrict__ out)
{
  __shared__ __align__(16) unsigned char smem[32768];
  unsigned short* As = (unsigned short*)smem;      // [64][32]
  unsigned short* Bs = As + 2048;                  // [128][32]
  float* Ct = (float*)smem;                        // [64][128] epilogue
  int blk = blockIdx.x;                            // 512 = 128 by x 4 bx
  int bx = blk & 3, by = blk >> 2;
  int tid = threadIdx.x, lane = tid & 63, w = tid >> 6;
  int wm = w >> 1, wn = w & 1;
  // staging: round 0 -> A chunks [0,256), rounds 1,2 -> B chunks [0,512)
  int ca = w*64 + lane;                 // A chunk
  int cb1 = w*64 + lane;                // B chunk round 1
  int cb2 = 256 + w*64 + lane;          // B chunk round 2
  const unsigned short* g0 = y   + ((size_t)(by*64  + (ca>>2)))*512 + (ca&3)*8;
  const unsigned short* g1 = wbf + ((size_t)(bx*128 + (cb1>>2)))*512 + (cb1&3)*8;
  const unsigned short* g2 = wbf + ((size_t)(bx*128 + (cb2>>2)))*512 + (cb2&3)*8;
  unsigned short* l0 = As + w*512;
  unsigned short* l1 = Bs + w*512;
  unsigned short* l2 = Bs + 2048 + w*512;
  f32x4 acc[2][4];
  #pragma unroll
  for (int i=0;i<2;++i)
    #pragma unroll
    for (int jj=0;jj<4;++jj)
      acc[i][jj] = (f32x4){0.f,0.f,0.f,0.f};
  int l15 = lane & 15, klo = (lane>>4)*8;
  for (int mslab = 0; mslab < 3; ++mslab){
    for (int kt = 0; kt < 16; ++kt){
      GLL16(g0, l0); GLL16(g1, l1); GLL16(g2, l2);
      g0 += 32; g1 += 32; g2 += 32;
      __syncthreads();
      short8 af[2], bfr[4];
      #pragma unroll
      for (int i=0;i<2;++i)
        af[i] = *(const short8*)(As + (wm*32 + i*16 + l15)*32 + klo);
      #pragma unroll
      for (int jj=0;jj<4;++jj)
        bfr[jj] = *(const short8*)(Bs + (wn*64 + jj*16 + l15)*32 + klo);
      #pragma unroll
      for (int i=0;i<2;++i)
        #pragma unroll
        for (int jj=0;jj<4;++jj)
          acc[i][jj] = __builtin_amdgcn_mfma_f32_16x16x32_bf16(af[i], bfr[jj], acc[i][jj], 0,0,0);
      __syncthreads();
    }
    if (mslab < 2){
      g0 += (size_t)SLAB_Y - 512;
      g1 += (size_t)SLAB_W - 512;
      g2 += (size_t)SLAB_W - 512;
    }
  }
  // epilogue: acc -> Ct (fp32), then out = x + Ct + sum_m sw_m*b_m
  int rbase = (lane>>4)*4;
  #pragma unroll
  for (int jj=0;jj<4;++jj){
    int col = wn*64 + jj*16 + l15;
    #pragma unroll
    for (int i=0;i<2;++i){
      int r0 = wm*32 + i*16 + rbase;
      #pragma unroll
      for (int rg=0;rg<4;++rg)
        Ct[(r0+rg)*128 + col] = acc[i][jj][rg];
    }
  }
  __syncthreads();
  #pragma unroll
  for (int q=0;q<8;++q){
    int R = q*8 + (tid>>5);
    int ch = (tid&31)*4;
    int grow = by*64 + R, gcol = bx*128 + ch;
    float4 cv = *(const float4*)(Ct + R*128 + ch);
    float4 xv = *(const float4*)(x + (size_t)grow*512 + gcol);
    float s0 = sw[grow], s1 = sw[8192 + grow], s2 = sw[16384 + grow];
    float4 b0 = *(const float4*)(bias + gcol);
    float4 b1 = *(const float4*)(bias + 512 + gcol);
    float4 b2 = *(const float4*)(bias + 1024 + gcol);
    float4 ov;
    ov.x = xv.x + cv.x + s0*b0.x + s1*b1.x + s2*b2.x;
    ov.y = xv.y + cv.y + s0*b0.y + s1*b1.y + s2*b2.y;
    ov.z = xv.z + cv.z + s0*b0.z + s1*b1.z + s2*b2.z;
    ov.w = xv.w + cv.w + s0*b0.w + s1*b1.w + s2*b2.w;
    *(float4*)(out + (size_t)grow*512 + gcol) = ov;
  }
}

extern "C" void kernel_launch(void* const* d_in, const int* in_sizes, int n_in,
                              void* d_out, int out_size, void* d_ws, size_t ws_size,
                              hipStream_t stream) {
  const float* x      = (const float*)d_in[0];
  const float* W      = (const float*)d_in[1];
  const float* bias   = (const float*)d_in[2];
  const float* alphas = (const float*)d_in[3];
  const float* betas  = (const float*)d_in[4];
  float* out = (float*)d_out;
  char* ws = (char*)d_ws;
  unsigned short* wbf  = (unsigned short*)ws;                         //  1,572,864 B
  float*          Gband= (float*)(ws + 1572864);                      //  1,048,576 B
  unsigned short* y    = (unsigned short*)(ws + 1572864 + 1048576);   // 25,165,824 B
  float*          sw   = (float*)(ws + 1572864 + 1048576 + 25165824); //     98,304 B

  k_gramw<<<1280, 256, 0, stream>>>(x, W, Gband, wbf);
  k_wsum <<<4096, 256, 0, stream>>>(x, Gband, alphas, betas, y, sw);
  k_gemm <<< 512, 256, 0, stream>>>(y, wbf, x, bias, sw, out);
}

// Round 7
// 65.580 us; speedup vs baseline: 1.1306x; 1.1306x over previous
//
#include <hip/hip_runtime.h>

typedef __attribute__((ext_vector_type(8))) short short8;
typedef __attribute__((ext_vector_type(4))) float f32x4;

#define S_LEN 1024
#define B_N 8
#define D_DIM 512
#define SLAB 4194304    // 8192*512 elements per tfm slab
#define NX   4194304    // x element count

static __device__ __forceinline__ unsigned short f2bf(float f){
  unsigned int u = __float_as_uint(f);
  u = u + 0x7fffu + ((u>>16)&1u);
  return (unsigned short)(u>>16);
}
static __device__ __forceinline__ float bf2f(unsigned short h){
  return __uint_as_float(((unsigned int)h)<<16);
}

#define GLL16(g,l) __builtin_amdgcn_global_load_lds( \
    (__attribute__((address_space(1))) void*)(g), \
    (__attribute__((address_space(3))) void*)(l), 16, 0, 0)

// hard barrier: compiler memory barrier + ISA barrier + sched fence both sides
#define SBAR() do { __builtin_amdgcn_sched_barrier(0); \
  asm volatile("s_barrier" ::: "memory"); \
  __builtin_amdgcn_sched_barrier(0); } while(0)
#define VMCNT0() asm volatile("s_waitcnt vmcnt(0)" ::: "memory")

// ---------------- fused convert: x and W -> bf16 (pure cast stream) ----------------
__global__ __launch_bounds__(256) void k_conv(const float* __restrict__ x,
    const float* __restrict__ W, unsigned short* __restrict__ xbf,
    unsigned short* __restrict__ wbf)
{
  size_t i = ((size_t)blockIdx.x*256 + threadIdx.x)*4;
  const float* src; unsigned short* dst;
  if (i < NX){ src = x + i; dst = xbf + i; }
  else       { src = W + (i - NX); dst = wbf + (i - NX); }
  float4 v = *(const float4*)src;
  ushort4 h;
  h.x = f2bf(v.x); h.y = f2bf(v.y); h.z = f2bf(v.z); h.w = f2bf(v.w);
  *(ushort4*)dst = h;
}

// ---------------- heavy: gemm blocks [0,768) + gram blocks [768,1280) ----------------
// gemm: C[m][row][j] = A[row,:]·W[m][j,:] + bias[m][j], tile 128x128 BK=32,
//       T3-minimum 2-phase dbuf: STAGE(next) || compute(cur); vmcnt(0)+barrier per iter
// gram: Gband[b][i][dl+14] = x[b,i]·x[b,i+dl], |dl|<=14
__global__ __launch_bounds__(256) void k_heavy(const unsigned short* __restrict__ A,
    const unsigned short* __restrict__ Bw, const float* __restrict__ bias,
    unsigned short* __restrict__ C, float* __restrict__ Gband)
{
  __shared__ __align__(16) unsigned short smem[16384]; // 32KB: 2x(As+Bs) dbuf / epilogue Ct alias
  int blk = blockIdx.x;
  int tid = threadIdx.x, lane = tid & 63, w = tid >> 6;

  if (blk >= 768){
    // ---- gram path (no barriers, no LDS) ----
    if (w >= 3) return;
    int g = blk - 768;
    int b = g & 7, i0 = (g >> 3) * 16;
    int j0 = i0 + (w - 1) * 16;
    if (j0 < 0 || j0 >= S_LEN) return;
    int l15 = lane & 15, klo = (lane >> 4) * 8;
    const unsigned short* Ar = A + ((size_t)(i0 + l15) * B_N + b) * D_DIM + klo;
    const unsigned short* Br = A + ((size_t)(j0 + l15) * B_N + b) * D_DIM + klo;
    f32x4 acc = (f32x4){0.f,0.f,0.f,0.f};
    #pragma unroll
    for (int kt = 0; kt < 16; ++kt){
      short8 af = *(const short8*)(Ar + kt*32);
      short8 bf = *(const short8*)(Br + kt*32);
      acc = __builtin_amdgcn_mfma_f32_16x16x32_bf16(af, bf, acc, 0,0,0);
    }
    int rb = (lane >> 4) * 4;
    #pragma unroll
    for (int rg = 0; rg < 4; ++rg){
      int i = i0 + rb + rg;
      int dl = j0 + l15 - i;
      if (dl >= -14 && dl <= 14)
        Gband[((size_t)b * S_LEN + i) * 32 + dl + 14] = acc[rg];
    }
    return;
  }

  // ---- gemm path ----
  // buffer q at smem + q*8192 elems: As = base..4096, Bs = base+4096..8192
  int bx = blk % 12, by = blk / 12;
  int wm = w >> 1, wn = w & 1;
  int c0 = w*128 + lane, c1 = c0 + 64;
  const unsigned short* gA0 = A + (size_t)(by*128 + (c0>>2))*512 + (c0&3)*8;
  const unsigned short* gA1 = A + (size_t)(by*128 + (c1>>2))*512 + (c1&3)*8;
  const unsigned short* gB0 = Bw + (size_t)(bx*128 + (c0>>2))*512 + (c0&3)*8;
  const unsigned short* gB1 = Bw + (size_t)(bx*128 + (c1>>2))*512 + (c1&3)*8;
  f32x4 acc[4][4];
  #pragma unroll
  for (int i=0;i<4;++i)
    #pragma unroll
    for (int j=0;j<4;++j)
      acc[i][j] = (f32x4){0.f,0.f,0.f,0.f};
  int l15 = lane & 15, klo = (lane>>4)*8;
  // prologue: stage tile 0 into buf 0, drain, barrier
  {
    unsigned short* s0 = smem + w*1024;
    GLL16(gA0, s0); GLL16(gA1, s0 + 512);
    GLL16(gB0, s0 + 4096); GLL16(gB1, s0 + 4096 + 512);
    gA0 += 32; gA1 += 32; gB0 += 32; gB1 += 32;
  }
  VMCNT0(); SBAR();
  #pragma unroll
  for (int kt = 0; kt < 16; ++kt){
    unsigned short* sc = smem + (kt & 1)*8192;
    if (kt < 15){
      unsigned short* sn = smem + ((kt + 1) & 1)*8192 + w*1024;
      GLL16(gA0, sn); GLL16(gA1, sn + 512);
      GLL16(gB0, sn + 4096); GLL16(gB1, sn + 4096 + 512);
      gA0 += 32; gA1 += 32; gB0 += 32; gB1 += 32;
    }
    short8 af[4], bfr[4];
    #pragma unroll
    for (int i=0;i<4;++i)
      af[i] = *(const short8*)(sc + (wm*64 + i*16 + l15)*32 + klo);
    #pragma unroll
    for (int j=0;j<4;++j)
      bfr[j] = *(const short8*)(sc + 4096 + (wn*64 + j*16 + l15)*32 + klo);
    #pragma unroll
    for (int i=0;i<4;++i)
      #pragma unroll
      for (int j=0;j<4;++j)
        acc[i][j] = __builtin_amdgcn_mfma_f32_16x16x32_bf16(af[i], bfr[j], acc[i][j], 0,0,0);
    if (kt < 15){
      // next tile fully landed + all waves done reading sc -> safe to swap
      __builtin_amdgcn_sched_barrier(0);
      VMCNT0();
      SBAR();
    }
  }
  // epilogue phase 1: acc + bias -> bf16 into LDS Ct[128][128] (full drain: Ct aliases bufs)
  __syncthreads();
  int rbase = (lane>>4)*4;
  #pragma unroll
  for (int j=0;j<4;++j){
    int nl = wn*64 + j*16 + l15;
    float bv = bias[bx*128 + nl];
    #pragma unroll
    for (int i=0;i<4;++i){
      int rl0 = wm*64 + i*16 + rbase;
      #pragma unroll
      for (int rg=0;rg<4;++rg)
        smem[(rl0+rg)*128 + nl] = f2bf(acc[i][j][rg] + bv);
    }
  }
  __syncthreads();
  // epilogue phase 2: coalesced 16B stores
  int m_r = bx >> 2, colb = (bx&3)*128;
  #pragma unroll
  for (int p=0;p<8;++p){
    int R = p*16 + (tid>>4);
    int ch = (tid&15)*8;
    uint4 v = *(const uint4*)(smem + R*128 + ch);
    *(uint4*)(C + (size_t)m_r*SLAB + (size_t)(by*128 + R)*512 + colb + ch) = v;
  }
}

// ---------------- fused weights + gather ----------------
// block 256 = 2 halves x 128 threads; half h handles (b, t=tg*2+h)
// sim(pos;t,m) = pp * rsqrt(G[pos][pos]) * rsqrt(sum_win pp)   [cnt cancels]
__global__ __launch_bounds__(256) void k_gath(const float* __restrict__ x,
    const unsigned short* __restrict__ tfm, const float* __restrict__ Gband,
    const float* __restrict__ alphas, const float* __restrict__ betas,
    float* __restrict__ out)
{
  int blk = blockIdx.x;           // 4096 = 8 b x 512 tg
  int b = blk & 7, tg = blk >> 3;
  int tid = threadIdx.x, h = tid >> 7, j = tid & 127;
  int t = tg * 2 + h;
  __shared__ float pshare[2][33];
  __shared__ float invc[2][3];
  __shared__ float wsh[2][33];
  int m = 0, pos = 0, valid = 0;
  float pp = 0.f, invnp = 0.f;
  if (j < 33){
    int r, wsl;
    if (j < 7){ m = 0; r = 3; wsl = j; }
    else if (j < 18){ m = 1; r = 5; wsl = j - 7; }
    else { m = 2; r = 7; wsl = j - 18; }
    pos = t + wsl - r;
    valid = (pos >= 0 && pos < S_LEN);
    if (valid){
      const float* grow = Gband + ((size_t)b * S_LEN + pos) * 32;
      int ulo = max(t - r, 0), uhi = min(t + r, S_LEN - 1);
      for (int u = ulo; u <= uhi; ++u) pp += grow[u - pos + 14];
      invnp = rsqrtf(fmaxf(grow[14], 1e-24f));
    }
    pshare[h][j] = valid ? pp : 0.f;
  }
  __syncthreads();
  if (j < 3){
    int s0 = j == 0 ? 0 : (j == 1 ? 7 : 18);
    int c  = j == 0 ? 7 : (j == 1 ? 11 : 15);
    float s = 0.f;
    for (int k = 0; k < c; ++k) s += pshare[h][s0 + k];
    invc[h][j] = rsqrtf(fmaxf(s, 1e-24f));
  }
  __syncthreads();
  if (j < 33){
    float wt = 0.f;
    if (valid){
      float sim = pp * invnp * invc[h][m];
      float z = alphas[m] * sim + betas[m];
      wt = 1.0f / (1.0f + expf(-z));
    }
    wsh[h][j] = wt;
  }
  __syncthreads();
  int d0 = j * 4;
  size_t xoff = ((size_t)t * B_N + b) * D_DIM + d0;
  float4 a = *(const float4*)(x + xoff);
  float ax = a.x, ay = a.y, az = a.z, aw = a.w;
  #pragma unroll
  for (int p = 0; p < 33; ++p){
    int pm, pr, wsl;
    if (p < 7){ pm = 0; pr = 3; wsl = p; }
    else if (p < 18){ pm = 1; pr = 5; wsl = p - 7; }
    else { pm = 2; pr = 7; wsl = p - 18; }
    int ppos = t + wsl - pr;
    if (ppos < 0 || ppos >= S_LEN) continue;
    float wt = wsh[h][p];
    const unsigned short* tp = tfm + (size_t)pm * SLAB + ((size_t)ppos * B_N + b) * D_DIM + d0;
    uint2 uv = *(const uint2*)tp;
    ax += wt * bf2f((unsigned short)(uv.x & 0xffffu));
    ay += wt * bf2f((unsigned short)(uv.x >> 16));
    az += wt * bf2f((unsigned short)(uv.y & 0xffffu));
    aw += wt * bf2f((unsigned short)(uv.y >> 16));
  }
  *(float4*)(out + xoff) = make_float4(ax, ay, az, aw);
}

extern "C" void kernel_launch(void* const* d_in, const int* in_sizes, int n_in,
                              void* d_out, int out_size, void* d_ws, size_t ws_size,
                              hipStream_t stream) {
  const float* x      = (const float*)d_in[0];
  const float* W      = (const float*)d_in[1];
  const float* bias   = (const float*)d_in[2];
  const float* alphas = (const float*)d_in[3];
  const float* betas  = (const float*)d_in[4];
  float* out = (float*)d_out;
  char* ws = (char*)d_ws;
  unsigned short* xbf  = (unsigned short*)ws;                               //  8,388,608 B
  unsigned short* wbf  = (unsigned short*)(ws + 8388608);                   //  1,572,864 B
  unsigned short* tfm  = (unsigned short*)(ws + 8388608 + 1572864);         // 25,165,824 B
  float*          Gband= (float*)(ws + 8388608 + 1572864 + 25165824);       //  1,048,576 B

  k_conv <<<4864, 256, 0, stream>>>(x, W, xbf, wbf);
  k_heavy<<<1280, 256, 0, stream>>>(xbf, wbf, bias, tfm, Gband);
  k_gath <<<4096, 256, 0, stream>>>(x, tfm, Gband, alphas, betas, out);
}

// Round 8
// 64.548 us; speedup vs baseline: 1.1487x; 1.0160x over previous
//
#include <hip/hip_runtime.h>

typedef __attribute__((ext_vector_type(8))) short short8;
typedef __attribute__((ext_vector_type(4))) float f32x4;

#define S_LEN 1024
#define B_N 8
#define D_DIM 512
#define SLAB 4194304    // 8192*512 elements per tfm slab
#define NX   4194304    // x element count

static __device__ __forceinline__ unsigned short f2bf(float f){
  unsigned int u = __float_as_uint(f);
  u = u + 0x7fffu + ((u>>16)&1u);
  return (unsigned short)(u>>16);
}
static __device__ __forceinline__ float bf2f(unsigned short h){
  return __uint_as_float(((unsigned int)h)<<16);
}

#define GLL16(g,l) __builtin_amdgcn_global_load_lds( \
    (__attribute__((address_space(1))) void*)(g), \
    (__attribute__((address_space(3))) void*)(l), 16, 0, 0)

// hard barrier: compiler memory barrier + ISA barrier + sched fence both sides
#define SBAR() do { __builtin_amdgcn_sched_barrier(0); \
  asm volatile("s_barrier" ::: "memory"); \
  __builtin_amdgcn_sched_barrier(0); } while(0)
#define VMCNT(n) asm volatile("s_waitcnt vmcnt(" #n ")" ::: "memory")

// ---------------- fused convert: x and W -> bf16 (pure cast stream) ----------------
__global__ __launch_bounds__(256) void k_conv(const float* __restrict__ x,
    const float* __restrict__ W, unsigned short* __restrict__ xbf,
    unsigned short* __restrict__ wbf)
{
  size_t i = ((size_t)blockIdx.x*256 + threadIdx.x)*4;
  const float* src; unsigned short* dst;
  if (i < NX){ src = x + i; dst = xbf + i; }
  else       { src = W + (i - NX); dst = wbf + (i - NX); }
  float4 v = *(const float4*)src;
  ushort4 h;
  h.x = f2bf(v.x); h.y = f2bf(v.y); h.z = f2bf(v.z); h.w = f2bf(v.w);
  *(ushort4*)dst = h;
}

// ---------------- heavy: gemm blocks [0,768) + gram blocks [768,1280) ----------------
// gemm: C[m][row][j] = A[row,:]·W[m][j,:] + bias[m][j], tile 128x128 BK=32,
//       3-buffer rotation, counted vmcnt(4) (tile kt+1 landed; kt+2 stays in flight)
// gram: Gband[b][i][dl+14] = x[b,i]·x[b,i+dl], |dl|<=14
__global__ __launch_bounds__(256) void k_heavy(const unsigned short* __restrict__ A,
    const unsigned short* __restrict__ Bw, const float* __restrict__ bias,
    unsigned short* __restrict__ C, float* __restrict__ Gband)
{
  __shared__ __align__(16) unsigned short smem[24576]; // 48KB: 3x(As+Bs) bufs / epilogue Ct alias
  int blk = blockIdx.x;
  int tid = threadIdx.x, lane = tid & 63, w = tid >> 6;

  if (blk >= 768){
    // ---- gram path (no barriers, no LDS) ----
    if (w >= 3) return;
    int g = blk - 768;
    int b = g & 7, i0 = (g >> 3) * 16;
    int j0 = i0 + (w - 1) * 16;
    if (j0 < 0 || j0 >= S_LEN) return;
    int l15 = lane & 15, klo = (lane >> 4) * 8;
    const unsigned short* Ar = A + ((size_t)(i0 + l15) * B_N + b) * D_DIM + klo;
    const unsigned short* Br = A + ((size_t)(j0 + l15) * B_N + b) * D_DIM + klo;
    f32x4 acc = (f32x4){0.f,0.f,0.f,0.f};
    #pragma unroll
    for (int kt = 0; kt < 16; ++kt){
      short8 af = *(const short8*)(Ar + kt*32);
      short8 bf = *(const short8*)(Br + kt*32);
      acc = __builtin_amdgcn_mfma_f32_16x16x32_bf16(af, bf, acc, 0,0,0);
    }
    int rb = (lane >> 4) * 4;
    #pragma unroll
    for (int rg = 0; rg < 4; ++rg){
      int i = i0 + rb + rg;
      int dl = j0 + l15 - i;
      if (dl >= -14 && dl <= 14)
        Gband[((size_t)b * S_LEN + i) * 32 + dl + 14] = acc[rg];
    }
    return;
  }

  // ---- gemm path ----
  // buffer q at smem + q*8192 elems: As = base..4096, Bs = base+4096..8192
  int bx = blk % 12, by = blk / 12;
  int wm = w >> 1, wn = w & 1;
  int c0 = w*128 + lane, c1 = c0 + 64;
  const unsigned short* gA0 = A + (size_t)(by*128 + (c0>>2))*512 + (c0&3)*8;
  const unsigned short* gA1 = A + (size_t)(by*128 + (c1>>2))*512 + (c1&3)*8;
  const unsigned short* gB0 = Bw + (size_t)(bx*128 + (c0>>2))*512 + (c0&3)*8;
  const unsigned short* gB1 = Bw + (size_t)(bx*128 + (c1>>2))*512 + (c1&3)*8;
  f32x4 acc[4][4];
  #pragma unroll
  for (int i=0;i<4;++i)
    #pragma unroll
    for (int j=0;j<4;++j)
      acc[i][j] = (f32x4){0.f,0.f,0.f,0.f};
  int l15 = lane & 15, klo = (lane>>4)*8;
  // prologue: stage tiles 0 and 1 into bufs 0 and 1; wait tile 0 (oldest 4 of 8)
  {
    unsigned short* s0 = smem + w*1024;
    GLL16(gA0, s0); GLL16(gA1, s0 + 512);
    GLL16(gB0, s0 + 4096); GLL16(gB1, s0 + 4096 + 512);
    gA0 += 32; gA1 += 32; gB0 += 32; gB1 += 32;
    unsigned short* s1 = smem + 8192 + w*1024;
    GLL16(gA0, s1); GLL16(gA1, s1 + 512);
    GLL16(gB0, s1 + 4096); GLL16(gB1, s1 + 4096 + 512);
    gA0 += 32; gA1 += 32; gB0 += 32; gB1 += 32;
  }
  VMCNT(4); SBAR();
  #pragma unroll
  for (int kt = 0; kt < 16; ++kt){
    unsigned short* sc = smem + (kt % 3)*8192;
    if (kt + 2 < 16){
      // stage tile kt+2 into buf[(kt+2)%3] == buf[(kt-1)%3] (reads done: prev barrier)
      unsigned short* sn = smem + ((kt + 2) % 3)*8192 + w*1024;
      GLL16(gA0, sn); GLL16(gA1, sn + 512);
      GLL16(gB0, sn + 4096); GLL16(gB1, sn + 4096 + 512);
      gA0 += 32; gA1 += 32; gB0 += 32; gB1 += 32;
    }
    short8 af[4], bfr[4];
    #pragma unroll
    for (int i=0;i<4;++i)
      af[i] = *(const short8*)(sc + (wm*64 + i*16 + l15)*32 + klo);
    #pragma unroll
    for (int j=0;j<4;++j)
      bfr[j] = *(const short8*)(sc + 4096 + (wn*64 + j*16 + l15)*32 + klo);
    #pragma unroll
    for (int i=0;i<4;++i)
      #pragma unroll
      for (int j=0;j<4;++j)
        acc[i][j] = __builtin_amdgcn_mfma_f32_16x16x32_bf16(af[i], bfr[j], acc[i][j], 0,0,0);
    if (kt < 15){
      __builtin_amdgcn_sched_barrier(0);
      if (kt + 2 < 16){ VMCNT(4); }   // tile kt+1 landed; kt+2 stays in flight
      else            { VMCNT(0); }   // kt=14: only tile 15's loads outstanding
      SBAR();
    }
  }
  // epilogue phase 1: acc + bias -> bf16 into LDS Ct[128][128] (Ct aliases bufs 0-1)
  __syncthreads();
  int rbase = (lane>>4)*4;
  #pragma unroll
  for (int j=0;j<4;++j){
    int nl = wn*64 + j*16 + l15;
    float bv = bias[bx*128 + nl];
    #pragma unroll
    for (int i=0;i<4;++i){
      int rl0 = wm*64 + i*16 + rbase;
      #pragma unroll
      for (int rg=0;rg<4;++rg)
        smem[(rl0+rg)*128 + nl] = f2bf(acc[i][j][rg] + bv);
    }
  }
  __syncthreads();
  // epilogue phase 2: coalesced 16B stores
  int m_r = bx >> 2, colb = (bx&3)*128;
  #pragma unroll
  for (int p=0;p<8;++p){
    int R = p*16 + (tid>>4);
    int ch = (tid&15)*8;
    uint4 v = *(const uint4*)(smem + R*128 + ch);
    *(uint4*)(C + (size_t)m_r*SLAB + (size_t)(by*128 + R)*512 + colb + ch) = v;
  }
}

// ---------------- fused weights + gather ----------------
// block 256 = 2 halves x 128 threads; half h handles (b, t=tg*2+h)
// sim(pos;t,m) = pp * rsqrt(G[pos][pos]) * rsqrt(sum_win pp)   [cnt cancels]
__global__ __launch_bounds__(256) void k_gath(const float* __restrict__ x,
    const unsigned short* __restrict__ tfm, const float* __restrict__ Gband,
    const float* __restrict__ alphas, const float* __restrict__ betas,
    float* __restrict__ out)
{
  int blk = blockIdx.x;           // 4096 = 8 b x 512 tg
  int b = blk & 7, tg = blk >> 3;
  int tid = threadIdx.x, h = tid >> 7, j = tid & 127;
  int t = tg * 2 + h;
  __shared__ float pshare[2][33];
  __shared__ float invc[2][3];
  __shared__ float wsh[2][33];
  int m = 0, pos = 0, valid = 0;
  float pp = 0.f, invnp = 0.f;
  if (j < 33){
    int r, wsl;
    if (j < 7){ m = 0; r = 3; wsl = j; }
    else if (j < 18){ m = 1; r = 5; wsl = j - 7; }
    else { m = 2; r = 7; wsl = j - 18; }
    pos = t + wsl - r;
    valid = (pos >= 0 && pos < S_LEN);
    if (valid){
      const float* grow = Gband + ((size_t)b * S_LEN + pos) * 32;
      int ulo = max(t - r, 0), uhi = min(t + r, S_LEN - 1);
      for (int u = ulo; u <= uhi; ++u) pp += grow[u - pos + 14];
      invnp = rsqrtf(fmaxf(grow[14], 1e-24f));
    }
    pshare[h][j] = valid ? pp : 0.f;
  }
  __syncthreads();
  if (j < 3){
    int s0 = j == 0 ? 0 : (j == 1 ? 7 : 18);
    int c  = j == 0 ? 7 : (j == 1 ? 11 : 15);
    float s = 0.f;
    for (int k = 0; k < c; ++k) s += pshare[h][s0 + k];
    invc[h][j] = rsqrtf(fmaxf(s, 1e-24f));
  }
  __syncthreads();
  if (j < 33){
    float wt = 0.f;
    if (valid){
      float sim = pp * invnp * invc[h][m];
      float z = alphas[m] * sim + betas[m];
      wt = 1.0f / (1.0f + expf(-z));
    }
    wsh[h][j] = wt;
  }
  __syncthreads();
  int d0 = j * 4;
  size_t xoff = ((size_t)t * B_N + b) * D_DIM + d0;
  float4 a = *(const float4*)(x + xoff);
  float ax = a.x, ay = a.y, az = a.z, aw = a.w;
  #pragma unroll
  for (int p = 0; p < 33; ++p){
    int pm, pr, wsl;
    if (p < 7){ pm = 0; pr = 3; wsl = p; }
    else if (p < 18){ pm = 1; pr = 5; wsl = p - 7; }
    else { pm = 2; pr = 7; wsl = p - 18; }
    int ppos = t + wsl - pr;
    if (ppos < 0 || ppos >= S_LEN) continue;
    float wt = wsh[h][p];
    const unsigned short* tp = tfm + (size_t)pm * SLAB + ((size_t)ppos * B_N + b) * D_DIM + d0;
    uint2 uv = *(const uint2*)tp;
    ax += wt * bf2f((unsigned short)(uv.x & 0xffffu));
    ay += wt * bf2f((unsigned short)(uv.x >> 16));
    az += wt * bf2f((unsigned short)(uv.y & 0xffffu));
    aw += wt * bf2f((unsigned short)(uv.y >> 16));
  }
  *(float4*)(out + xoff) = make_float4(ax, ay, az, aw);
}

extern "C" void kernel_launch(void* const* d_in, const int* in_sizes, int n_in,
                              void* d_out, int out_size, void* d_ws, size_t ws_size,
                              hipStream_t stream) {
  const float* x      = (const float*)d_in[0];
  const float* W      = (const float*)d_in[1];
  const float* bias   = (const float*)d_in[2];
  const float* alphas = (const float*)d_in[3];
  const float* betas  = (const float*)d_in[4];
  float* out = (float*)d_out;
  char* ws = (char*)d_ws;
  unsigned short* xbf  = (unsigned short*)ws;                               //  8,388,608 B
  unsigned short* wbf  = (unsigned short*)(ws + 8388608);                   //  1,572,864 B
  unsigned short* tfm  = (unsigned short*)(ws + 8388608 + 1572864);         // 25,165,824 B
  float*          Gband= (float*)(ws + 8388608 + 1572864 + 25165824);       //  1,048,576 B

  k_conv <<<4864, 256, 0, stream>>>(x, W, xbf, wbf);
  k_heavy<<<1280, 256, 0, stream>>>(xbf, wbf, bias, tfm, Gband);
  k_gath <<<4096, 256, 0, stream>>>(x, tfm, Gband, alphas, betas, out);
}

// Round 9
// 63.394 us; speedup vs baseline: 1.1696x; 1.0182x over previous
//
#include <hip/hip_runtime.h>

typedef __attribute__((ext_vector_type(8))) short short8;
typedef __attribute__((ext_vector_type(4))) float f32x4;

#define S_LEN 1024
#define B_N 8
#define D_DIM 512
#define SLAB 4194304    // 8192*512 elements per tfm slab
#define NX   4194304    // x element count

static __device__ __forceinline__ unsigned short f2bf(float f){
  unsigned int u = __float_as_uint(f);
  u = u + 0x7fffu + ((u>>16)&1u);
  return (unsigned short)(u>>16);
}
static __device__ __forceinline__ float bf2f(unsigned short h){
  return __uint_as_float(((unsigned int)h)<<16);
}

#define GLL16(g,l) __builtin_amdgcn_global_load_lds( \
    (__attribute__((address_space(1))) void*)(g), \
    (__attribute__((address_space(3))) void*)(l), 16, 0, 0)

// hard barrier: compiler memory barrier + ISA barrier + sched fence both sides
#define SBAR() do { __builtin_amdgcn_sched_barrier(0); \
  asm volatile("s_barrier" ::: "memory"); \
  __builtin_amdgcn_sched_barrier(0); } while(0)
#define VMCNT(n) asm volatile("s_waitcnt vmcnt(" #n ")" ::: "memory")

// ---------------- fused convert: x and W -> bf16 (pure cast stream) ----------------
__global__ __launch_bounds__(256) void k_conv(const float* __restrict__ x,
    const float* __restrict__ W, unsigned short* __restrict__ xbf,
    unsigned short* __restrict__ wbf)
{
  size_t i = ((size_t)blockIdx.x*256 + threadIdx.x)*4;
  const float* src; unsigned short* dst;
  if (i < NX){ src = x + i; dst = xbf + i; }
  else       { src = W + (i - NX); dst = wbf + (i - NX); }
  float4 v = *(const float4*)src;
  ushort4 h;
  h.x = f2bf(v.x); h.y = f2bf(v.y); h.z = f2bf(v.z); h.w = f2bf(v.w);
  *(ushort4*)dst = h;
}

// ---------------- heavy: gemm blocks [0,768) + gram blocks [768,1280) ----------------
// gemm: C[m][row][j] = A[row,:]·W[m][j,:] + bias[m][j], tile 128x128 BK=32,
//       3-buffer rotation, counted vmcnt(4); XCD-chunked (by,bx) swizzle:
//       xcd = blk&7 owns by in [xcd*8, xcd*8+8) x all 12 bx -> A-tile fetched
//       into ONE XCD's L2 instead of ~8 (A re-fetch ~67MB -> 8.4MB).
// gram: Gband[b][i][dl+14] = x[b,i]·x[b,i+dl], |dl|<=14
__global__ __launch_bounds__(256) void k_heavy(const unsigned short* __restrict__ A,
    const unsigned short* __restrict__ Bw, const float* __restrict__ bias,
    unsigned short* __restrict__ C, float* __restrict__ Gband)
{
  __shared__ __align__(16) unsigned short smem[24576]; // 48KB: 3x(As+Bs) bufs / epilogue Ct alias
  int blk = blockIdx.x;
  int tid = threadIdx.x, lane = tid & 63, w = tid >> 6;

  if (blk >= 768){
    // ---- gram path (no barriers, no LDS) ----
    if (w >= 3) return;
    int g = blk - 768;
    int b = g & 7, i0 = (g >> 3) * 16;
    int j0 = i0 + (w - 1) * 16;
    if (j0 < 0 || j0 >= S_LEN) return;
    int l15 = lane & 15, klo = (lane >> 4) * 8;
    const unsigned short* Ar = A + ((size_t)(i0 + l15) * B_N + b) * D_DIM + klo;
    const unsigned short* Br = A + ((size_t)(j0 + l15) * B_N + b) * D_DIM + klo;
    f32x4 acc = (f32x4){0.f,0.f,0.f,0.f};
    #pragma unroll
    for (int kt = 0; kt < 16; ++kt){
      short8 af = *(const short8*)(Ar + kt*32);
      short8 bf = *(const short8*)(Br + kt*32);
      acc = __builtin_amdgcn_mfma_f32_16x16x32_bf16(af, bf, acc, 0,0,0);
    }
    int rb = (lane >> 4) * 4;
    #pragma unroll
    for (int rg = 0; rg < 4; ++rg){
      int i = i0 + rb + rg;
      int dl = j0 + l15 - i;
      if (dl >= -14 && dl <= 14)
        Gband[((size_t)b * S_LEN + i) * 32 + dl + 14] = acc[rg];
    }
    return;
  }

  // ---- gemm path ----
  // XCD-chunked swizzle (bijective on [0,768)): assumes round-robin blockIdx->XCD
  int xcd = blk & 7, ixc = blk >> 3;        // ixc in [0,96)
  int by = xcd * 8 + ixc / 12;              // 8 A-tiles per XCD
  int bx = ixc % 12;
  int wm = w >> 1, wn = w & 1;
  int c0 = w*128 + lane, c1 = c0 + 64;
  const unsigned short* gA0 = A + (size_t)(by*128 + (c0>>2))*512 + (c0&3)*8;
  const unsigned short* gA1 = A + (size_t)(by*128 + (c1>>2))*512 + (c1&3)*8;
  const unsigned short* gB0 = Bw + (size_t)(bx*128 + (c0>>2))*512 + (c0&3)*8;
  const unsigned short* gB1 = Bw + (size_t)(bx*128 + (c1>>2))*512 + (c1&3)*8;
  f32x4 acc[4][4];
  #pragma unroll
  for (int i=0;i<4;++i)
    #pragma unroll
    for (int j=0;j<4;++j)
      acc[i][j] = (f32x4){0.f,0.f,0.f,0.f};
  int l15 = lane & 15, klo = (lane>>4)*8;
  // prologue: stage tiles 0 and 1 into bufs 0 and 1; wait tile 0 (oldest 4 of 8)
  {
    unsigned short* s0 = smem + w*1024;
    GLL16(gA0, s0); GLL16(gA1, s0 + 512);
    GLL16(gB0, s0 + 4096); GLL16(gB1, s0 + 4096 + 512);
    gA0 += 32; gA1 += 32; gB0 += 32; gB1 += 32;
    unsigned short* s1 = smem + 8192 + w*1024;
    GLL16(gA0, s1); GLL16(gA1, s1 + 512);
    GLL16(gB0, s1 + 4096); GLL16(gB1, s1 + 4096 + 512);
    gA0 += 32; gA1 += 32; gB0 += 32; gB1 += 32;
  }
  VMCNT(4); SBAR();
  #pragma unroll
  for (int kt = 0; kt < 16; ++kt){
    unsigned short* sc = smem + (kt % 3)*8192;
    if (kt + 2 < 16){
      // stage tile kt+2 into buf[(kt+2)%3] == buf[(kt-1)%3] (reads done: prev barrier)
      unsigned short* sn = smem + ((kt + 2) % 3)*8192 + w*1024;
      GLL16(gA0, sn); GLL16(gA1, sn + 512);
      GLL16(gB0, sn + 4096); GLL16(gB1, sn + 4096 + 512);
      gA0 += 32; gA1 += 32; gB0 += 32; gB1 += 32;
    }
    short8 af[4], bfr[4];
    #pragma unroll
    for (int i=0;i<4;++i)
      af[i] = *(const short8*)(sc + (wm*64 + i*16 + l15)*32 + klo);
    #pragma unroll
    for (int j=0;j<4;++j)
      bfr[j] = *(const short8*)(sc + 4096 + (wn*64 + j*16 + l15)*32 + klo);
    #pragma unroll
    for (int i=0;i<4;++i)
      #pragma unroll
      for (int j=0;j<4;++j)
        acc[i][j] = __builtin_amdgcn_mfma_f32_16x16x32_bf16(af[i], bfr[j], acc[i][j], 0,0,0);
    if (kt < 15){
      __builtin_amdgcn_sched_barrier(0);
      if (kt + 2 < 16){ VMCNT(4); }   // tile kt+1 landed; kt+2 stays in flight
      else            { VMCNT(0); }   // kt=14: only tile 15's loads outstanding
      SBAR();
    }
  }
  // epilogue phase 1: acc + bias -> bf16 into LDS Ct[128][128] (Ct aliases bufs 0-1)
  __syncthreads();
  int rbase = (lane>>4)*4;
  #pragma unroll
  for (int j=0;j<4;++j){
    int nl = wn*64 + j*16 + l15;
    float bv = bias[bx*128 + nl];
    #pragma unroll
    for (int i=0;i<4;++i){
      int rl0 = wm*64 + i*16 + rbase;
      #pragma unroll
      for (int rg=0;rg<4;++rg)
        smem[(rl0+rg)*128 + nl] = f2bf(acc[i][j][rg] + bv);
    }
  }
  __syncthreads();
  // epilogue phase 2: coalesced 16B stores
  int m_r = bx >> 2, colb = (bx&3)*128;
  #pragma unroll
  for (int p=0;p<8;++p){
    int R = p*16 + (tid>>4);
    int ch = (tid&15)*8;
    uint4 v = *(const uint4*)(smem + R*128 + ch);
    *(uint4*)(C + (size_t)m_r*SLAB + (size_t)(by*128 + R)*512 + colb + ch) = v;
  }
}

// ---------------- fused weights + gather ----------------
// block 256 = 2 halves x 128 threads; half h handles (b, t=tg*2+h)
// sim(pos;t,m) = pp * rsqrt(G[pos][pos]) * rsqrt(sum_win pp)   [cnt cancels]
__global__ __launch_bounds__(256) void k_gath(const float* __restrict__ x,
    const unsigned short* __restrict__ tfm, const float* __restrict__ Gband,
    const float* __restrict__ alphas, const float* __restrict__ betas,
    float* __restrict__ out)
{
  int blk = blockIdx.x;           // 4096 = 8 b x 512 tg
  int b = blk & 7, tg = blk >> 3;
  int tid = threadIdx.x, h = tid >> 7, j = tid & 127;
  int t = tg * 2 + h;
  __shared__ float pshare[2][33];
  __shared__ float invc[2][3];
  __shared__ float wsh[2][33];
  int m = 0, pos = 0, valid = 0;
  float pp = 0.f, invnp = 0.f;
  if (j < 33){
    int r, wsl;
    if (j < 7){ m = 0; r = 3; wsl = j; }
    else if (j < 18){ m = 1; r = 5; wsl = j - 7; }
    else { m = 2; r = 7; wsl = j - 18; }
    pos = t + wsl - r;
    valid = (pos >= 0 && pos < S_LEN);
    if (valid){
      const float* grow = Gband + ((size_t)b * S_LEN + pos) * 32;
      int ulo = max(t - r, 0), uhi = min(t + r, S_LEN - 1);
      for (int u = ulo; u <= uhi; ++u) pp += grow[u - pos + 14];
      invnp = rsqrtf(fmaxf(grow[14], 1e-24f));
    }
    pshare[h][j] = valid ? pp : 0.f;
  }
  __syncthreads();
  if (j < 3){
    int s0 = j == 0 ? 0 : (j == 1 ? 7 : 18);
    int c  = j == 0 ? 7 : (j == 1 ? 11 : 15);
    float s = 0.f;
    for (int k = 0; k < c; ++k) s += pshare[h][s0 + k];
    invc[h][j] = rsqrtf(fmaxf(s, 1e-24f));
  }
  __syncthreads();
  if (j < 33){
    float wt = 0.f;
    if (valid){
      float sim = pp * invnp * invc[h][m];
      float z = alphas[m] * sim + betas[m];
      wt = 1.0f / (1.0f + expf(-z));
    }
    wsh[h][j] = wt;
  }
  __syncthreads();
  int d0 = j * 4;
  size_t xoff = ((size_t)t * B_N + b) * D_DIM + d0;
  float4 a = *(const float4*)(x + xoff);
  float ax = a.x, ay = a.y, az = a.z, aw = a.w;
  #pragma unroll
  for (int p = 0; p < 33; ++p){
    int pm, pr, wsl;
    if (p < 7){ pm = 0; pr = 3; wsl = p; }
    else if (p < 18){ pm = 1; pr = 5; wsl = p - 7; }
    else { pm = 2; pr = 7; wsl = p - 18; }
    int ppos = t + wsl - pr;
    if (ppos < 0 || ppos >= S_LEN) continue;
    float wt = wsh[h][p];
    const unsigned short* tp = tfm + (size_t)pm * SLAB + ((size_t)ppos * B_N + b) * D_DIM + d0;
    uint2 uv = *(const uint2*)tp;
    ax += wt * bf2f((unsigned short)(uv.x & 0xffffu));
    ay += wt * bf2f((unsigned short)(uv.x >> 16));
    az += wt * bf2f((unsigned short)(uv.y & 0xffffu));
    aw += wt * bf2f((unsigned short)(uv.y >> 16));
  }
  *(float4*)(out + xoff) = make_float4(ax, ay, az, aw);
}

extern "C" void kernel_launch(void* const* d_in, const int* in_sizes, int n_in,
                              void* d_out, int out_size, void* d_ws, size_t ws_size,
                              hipStream_t stream) {
  const float* x      = (const float*)d_in[0];
  const float* W      = (const float*)d_in[1];
  const float* bias   = (const float*)d_in[2];
  const float* alphas = (const float*)d_in[3];
  const float* betas  = (const float*)d_in[4];
  float* out = (float*)d_out;
  char* ws = (char*)d_ws;
  unsigned short* xbf  = (unsigned short*)ws;                               //  8,388,608 B
  unsigned short* wbf  = (unsigned short*)(ws + 8388608);                   //  1,572,864 B
  unsigned short* tfm  = (unsigned short*)(ws + 8388608 + 1572864);         // 25,165,824 B
  float*          Gband= (float*)(ws + 8388608 + 1572864 + 25165824);       //  1,048,576 B

  k_conv <<<4864, 256, 0, stream>>>(x, W, xbf, wbf);
  k_heavy<<<1280, 256, 0, stream>>>(xbf, wbf, bias, tfm, Gband);
  k_gath <<<4096, 256, 0, stream>>>(x, tfm, Gband, alphas, betas, out);
}